// Round 2
// 217.811 us; speedup vs baseline: 1.0368x; 1.0368x over previous
//
#include <hip/hip_runtime.h>

// ============================================================================
// ContDecoder on MI355X — bf16 MFMA, round 4 (resubmit; round-4 bench died
// to a container infra failure, no kernel evidence).
// MPTS=32 points/block, 1024 threads (16 waves), 55.8 KB dynamic LDS,
// ** 2 blocks/CU ** (32 waves = 100% occupancy, two barrier domains).
// Round-3 was latency-bound at 1 block/CU: barriers, the VALU sampling
// prologue, and tiny tail layers idled the MFMA pipe (MfmaUtil 17%).
// With two resident blocks, one block's MFMA work covers the other's
// stalls. Packed-B fragments are still loaded exactly once per block
// (NG=1, MS=MTILES -> MGRP=1 for every layer).
//
// LDS row layout per point (bf16): [xin 0..64 | hA 64..608 | hB 608..864],
// stride 872 elems. Stale bytes in reused regions are masked by zero-packed
// weight rows; pad neurons get bias 0 so they write exact zeros.
// ============================================================================

#define NTH     1024
#define NWAVES  16
#define MPTS    32              // points per block (2 m-tiles of 16)
#define MTILES  (MPTS / 16)
#define SROW    872             // LDS row stride in bf16 elems
#define XIN_OFF 0
#define HA_OFF  64
#define HB_OFF  608
#define NPOINTS (8 * 16384)
#define GRIDX   (NPOINTS / MPTS)   // 4096 blocks
#define LDSBYTES (MPTS * SROW * 2) // 55808 -> 2 blocks/CU

typedef short          short8 __attribute__((ext_vector_type(8)));
typedef float          f32x4  __attribute__((ext_vector_type(4)));
typedef unsigned short u16;

__device__ __forceinline__ u16 f2bf(float f) {
    unsigned int u = __builtin_bit_cast(unsigned int, f);
    u += 0x7fffu + ((u >> 16) & 1u);        // round-to-nearest-even
    return (u16)(u >> 16);
}

// ---------------------------------------------------------------------------
// Packed-weight geometry (16B fragments of 8 bf16). frag (l, nt, s, lane)
// holds B[s*32 + (lane>>4)*8 + j][nt*16 + (lane&15)], j=0..7, zero-padded.
//   l : KHpad KSteps Ntiles  frag_base
//   0 :    0    2     33        0
//   1 :  544   19     16     4224
//   2 :  256   10      8    23680
//   3 :  128    6      4    28800
//   4 :   64    4      2    30336
//   5 :   32    3      1    30848
//   6 :   32    1      1    31040   total 31104 frags = 497664 B in d_ws
// ---------------------------------------------------------------------------
__constant__ int pk_base8[8] = {0, 4224, 23680, 28800, 30336, 30848, 31040, 31104};
__constant__ int pk_ks[7]    = {2, 19, 10, 6, 4, 3, 1};
__constant__ int pk_khp[7]   = {0, 544, 256, 128, 64, 32, 32};
__constant__ int pk_kact[7]  = {0, 516, 256, 128, 64, 32, 16};
__constant__ int pk_nact[7]  = {516, 256, 128, 64, 32, 16, 2};

struct WPtrs { const float* W[7]; };

// One thread = one 16B fragment. Reads coalesce across lanes (consecutive n
// for fixed j,k); writes are perfectly coalesced 16B/lane.
__global__ void pack_weights(WPtrs wp, u16* __restrict__ out)
{
    const int f = blockIdx.x * blockDim.x + threadIdx.x;
    if (f >= 31104) return;
    int l = 0;
    while (l < 6 && f >= pk_base8[l + 1]) ++l;
    const int r    = f - pk_base8[l];
    const int lane = r & 63;
    const int t    = r >> 6;
    const int ks   = pk_ks[l];
    const int s    = t % ks;
    const int nt   = t / ks;
    const int n    = nt * 16 + (lane & 15);
    const int k0   = s * 32 + (lane >> 4) * 8;
    const int nact = pk_nact[l];
    const int khp  = pk_khp[l];
    const int kact = pk_kact[l];
    const float* W = wp.W[l];

    union { short8 v; u16 e[8]; } frag;
#pragma unroll
    for (int j = 0; j < 8; ++j) {
        const int k = k0 + j;
        float v = 0.0f;
        if (n < nact) {
            if (k < khp) {
                if (k < kact) v = W[k * nact + n];
            } else {
                const int xr = k - khp;
                if (xr < 37) v = W[(kact + xr) * nact + n];
            }
        }
        frag.e[j] = f2bf(v);
    }
    *(short8*)(out + (size_t)f * 8) = frag.v;
}

// ---------------------------------------------------------------------------
// One MLP layer. Unit = (n-group of NG tiles) x (m-group of MS tiles of 16
// points). Units strided across 16 waves. B frags from global (L2), A frags
// from LDS rows, D written back to LDS (or global for the last layer).
// C/D layout: row = (lane>>4)*4 + r, col = lane&15  (m89-verified).
// ---------------------------------------------------------------------------
template<int KHP, int HSEG, int OSEG, int NT, int NG, int MS, int NACT,
         int LBASE, bool XIN, bool RELU, bool GOUT>
__device__ __forceinline__ void mlayer(const u16* __restrict__ wpack,
                                       const float* __restrict__ bias,
                                       u16* __restrict__ s_act,
                                       float* __restrict__ gout, int p0,
                                       int wave, int lane)
{
    constexpr int KHS   = KHP / 32;
    constexpr int KS    = KHS + (XIN ? 2 : 0);
    constexpr int NGRP  = (NT + NG - 1) / NG;
    constexpr int MGRP  = MTILES / MS;       // = 1 for all layers (MS=MTILES)
    constexpr int UNITS = NGRP * MGRP;
    const int lm = lane & 15;
    const int lq = lane >> 4;
    const u16* wbase = wpack + LBASE + lane * 8;

    for (int u = wave; u < UNITS; u += NWAVES) {
        const int gn = u % NGRP;
        const int gm = u / NGRP;
        const int n0 = gn * NG;
        const int m0 = gm * MS;

        const u16* arow[MS];
#pragma unroll
        for (int m = 0; m < MS; ++m)
            arow[m] = s_act + ((m0 + m) * 16 + lm) * SROW + lq * 8;

        f32x4 acc[NG][MS];
#pragma unroll
        for (int t = 0; t < NG; ++t)
#pragma unroll
            for (int m = 0; m < MS; ++m)
                acc[t][m] = (f32x4){0.f, 0.f, 0.f, 0.f};

#pragma unroll
        for (int s = 0; s < KS; ++s) {
            const int ab = (s < KHS) ? (HSEG + s * 32)
                                     : (XIN_OFF + (s - KHS) * 32);
            short8 a[MS];
#pragma unroll
            for (int m = 0; m < MS; ++m)
                a[m] = *(const short8*)(arow[m] + ab);
#pragma unroll
            for (int t = 0; t < NG; ++t) {
                const int nt = n0 + t;
                if ((NT % NG) && nt >= NT) break;
                const short8 b = *(const short8*)(wbase + (size_t)(nt * KS + s) * 512);
#pragma unroll
                for (int m = 0; m < MS; ++m)
                    acc[t][m] = __builtin_amdgcn_mfma_f32_16x16x32_bf16(a[m], b, acc[t][m], 0, 0, 0);
            }
        }

#pragma unroll
        for (int t = 0; t < NG; ++t) {
            const int nt = n0 + t;
            if ((NT % NG) && nt >= NT) break;
            const int n = nt * 16 + lm;
            const float bv = (n < NACT) ? bias[n] : 0.f;   // pad neurons -> 0
#pragma unroll
            for (int m = 0; m < MS; ++m) {
#pragma unroll
                for (int r = 0; r < 4; ++r) {
                    float v = acc[t][m][r] + bv;
                    if (RELU) v = fmaxf(v, 0.f);
                    const int pt = (m0 + m) * 16 + lq * 4 + r;
                    if (GOUT) {
                        if (n < NACT)
                            gout[(size_t)(p0 + pt) * 2 + n] = v;
                    } else {
                        s_act[pt * SROW + OSEG + n] = f2bf(v);
                    }
                }
            }
        }
    }
}

struct MainParams {
    const float* lr;     // [B,2,64,64]
    const float* ctx;    // [B,32,64,64]
    const float* eps;    // [B,64,64]
    const float* coord;  // [B,N,2]
    const float* Bb[7];  // biases (fp32)
    const u16*   wpack;  // packed bf16 weights in d_ws
    float*       out;    // [B,N,2]
};

__global__ __launch_bounds__(NTH, 8)   // 8 waves/EU = 32 waves/CU = 2 blocks
void cont_decoder_mfma(MainParams p)
{
    extern __shared__ u16 s_act[];         // MPTS*SROW bf16 = 55808 B
    __shared__ int   s_x0[MPTS], s_y0[MPTS];
    __shared__ float s_wx[MPTS], s_wy[MPTS];

    const int tid  = threadIdx.x;
    const int wave = tid >> 6;
    const int lane = tid & 63;
    const int p0   = blockIdx.x * MPTS;
    const int b    = p0 >> 14;             // 16384 points per batch

    // ---- zero pad regions: xin[37..64) and hA[528..544) (cols 592..608) ----
    for (int i = tid; i < MPTS * 43; i += NTH) {
        const int pt = i / 43, c = i % 43;
        const int col = (c < 27) ? (37 + c) : (592 + (c - 27));
        s_act[pt * SROW + col] = 0;
    }

    // ---- bilinear params + coord features ----
    if (tid < MPTS) {
        const int pt = p0 + tid;
        const float cx = p.coord[2 * pt];
        const float cy = p.coord[2 * pt + 1];
        const float gx = (cx + 1.0f) * 32.0f - 0.5f;   // align_corners=False
        const float gy = (cy + 1.0f) * 32.0f - 0.5f;
        const float fx0 = floorf(gx), fy0 = floorf(gy);
        s_x0[tid] = (int)fx0;
        s_y0[tid] = (int)fy0;
        s_wx[tid] = gx - fx0;
        s_wy[tid] = gy - fy0;
        s_act[tid * SROW + 32] = f2bf(cx);
        s_act[tid * SROW + 33] = f2bf(cy);
    }
    __syncthreads();

    // ---- sample 35 channels/point (ref swaps spatial axes: val = g[b,c,x,y]) ----
    for (int idx = tid; idx < MPTS * 35; idx += NTH) {
        const int t = idx / 35;
        const int c = idx % 35;
        const float* base;
        int col;
        if (c < 32)      { base = p.ctx + (size_t)(b * 32 + c) * 4096;       col = c; }
        else if (c < 34) { base = p.lr  + (size_t)(b * 2 + (c - 32)) * 4096; col = 34 + (c - 32); }
        else             { base = p.eps + (size_t)b * 4096;                   col = 36; }

        const int   x0 = s_x0[t], y0 = s_y0[t];
        const float wx = s_wx[t], wy = s_wy[t];
        const int x1 = x0 + 1, y1 = y0 + 1;
        const bool xv0 = (x0 >= 0) & (x0 < 64);
        const bool xv1 = (x1 >= 0) & (x1 < 64);
        const bool yv0 = (y0 >= 0) & (y0 < 64);
        const bool yv1 = (y1 >= 0) & (y1 < 64);
        const int xc0 = min(max(x0, 0), 63), xc1 = min(max(x1, 0), 63);
        const int yc0 = min(max(y0, 0), 63), yc1 = min(max(y1, 0), 63);

        const float w00 = (1.0f - wx) * (1.0f - wy) * ((xv0 && yv0) ? 1.0f : 0.0f);
        const float w10 = wx * (1.0f - wy)          * ((xv1 && yv0) ? 1.0f : 0.0f);
        const float w01 = (1.0f - wx) * wy          * ((xv0 && yv1) ? 1.0f : 0.0f);
        const float w11 = wx * wy                   * ((xv1 && yv1) ? 1.0f : 0.0f);

        const float val = w00 * base[xc0 * 64 + yc0]
                        + w10 * base[xc1 * 64 + yc0]
                        + w01 * base[xc0 * 64 + yc1]
                        + w11 * base[xc1 * 64 + yc1];
        s_act[t * SROW + col] = f2bf(val);
    }
    __syncthreads();

    // ---- MLP:  xin(37p64) ->W0-> hA(516p528) ->W1-> hB(256) ->W2-> hA(128)
    //            ->W3-> hB(64) ->W4-> hA(32) ->W5-> hB(16) ->W6-> out(2)
    //       KHP  HSEG    OSEG    NT  NG MS NACT LBASE(elems) XIN   RELU  GOUT
    mlayer<  0,  HA_OFF, HA_OFF, 33, 1, 2, 516, 0,      true,  true,  false>(p.wpack, p.Bb[0], s_act, nullptr, p0, wave, lane);
    __syncthreads();
    mlayer<544,  HA_OFF, HB_OFF, 16, 1, 2, 256, 33792,  true,  true,  false>(p.wpack, p.Bb[1], s_act, nullptr, p0, wave, lane);
    __syncthreads();
    mlayer<256,  HB_OFF, HA_OFF,  8, 1, 2, 128, 189440, true,  true,  false>(p.wpack, p.Bb[2], s_act, nullptr, p0, wave, lane);
    __syncthreads();
    mlayer<128,  HA_OFF, HB_OFF,  4, 1, 2,  64, 230400, true,  true,  false>(p.wpack, p.Bb[3], s_act, nullptr, p0, wave, lane);
    __syncthreads();
    mlayer< 64,  HB_OFF, HA_OFF,  2, 1, 2,  32, 242688, true,  true,  false>(p.wpack, p.Bb[4], s_act, nullptr, p0, wave, lane);
    __syncthreads();
    mlayer< 32,  HA_OFF, HB_OFF,  1, 1, 2,  16, 246784, true,  true,  false>(p.wpack, p.Bb[5], s_act, nullptr, p0, wave, lane);
    __syncthreads();
    mlayer< 32,  HB_OFF, 0,       1, 1, 2,   2, 248320, false, false, true >(p.wpack, p.Bb[6], s_act, p.out,   p0, wave, lane);
}

extern "C" void kernel_launch(void* const* d_in, const int* in_sizes, int n_in,
                              void* d_out, int out_size, void* d_ws, size_t ws_size,
                              hipStream_t stream)
{
    WPtrs wp;
    for (int l = 0; l < 7; ++l) wp.W[l] = (const float*)d_in[4 + 2 * l];

    MainParams p;
    p.lr    = (const float*)d_in[0];
    p.ctx   = (const float*)d_in[1];
    p.eps   = (const float*)d_in[2];
    p.coord = (const float*)d_in[3];
    for (int l = 0; l < 7; ++l) p.Bb[l] = (const float*)d_in[5 + 2 * l];
    p.wpack = (const u16*)d_ws;
    p.out   = (float*)d_out;

    // Opt in to large dynamic LDS (idempotent; not a stream op, capture-safe).
    hipFuncSetAttribute((const void*)cont_decoder_mfma,
                        hipFuncAttributeMaxDynamicSharedMemorySize, LDSBYTES);

    hipLaunchKernelGGL(pack_weights, dim3(122), dim3(256), 0, stream, wp, (u16*)d_ws);
    hipLaunchKernelGGL(cont_decoder_mfma, dim3(GRIDX), dim3(NTH), LDSBYTES, stream, p);
}